// Round 1
// baseline (2019.646 us; speedup 1.0000x reference)
//
#include <hip/hip_runtime.h>
#include <hip/hip_bf16.h>

#define NPTS 120000
#define CC   128
#define HIMG 192
#define WIMG 640
#define HWPX (HIMG * WIMG)
#define IMIN (-2147483647 - 1)

// ---------------------------------------------------------------- helpers

__device__ __forceinline__ float f4get(const float4& v, int j) {
  switch (j) { case 0: return v.x; case 1: return v.y; case 2: return v.z; default: return v.w; }
}

// stage transposed weight chunk: wt[k][c] = W[(rowbase+c)*rowlen + kc + k], k<32, c<128
__device__ __forceinline__ void stage_wt(float (*wt)[132], const float* __restrict__ W,
                                         int rowlen, int rowbase, int kc, int tid) {
#pragma unroll
  for (int i = 0; i < 16; ++i) {
    int idx = tid + i * 256;
    int c = idx >> 5, k = idx & 31;
    wt[k][c] = W[(size_t)(rowbase + c) * rowlen + kc + k];
  }
}

// acc[i][j] += sum_{k<32} A[p0+i][kc+k] * wt[k][c0+j]
__device__ __forceinline__ void tile_fma(const float (*A)[132], int p0, int kc,
                                         const float (*wt)[132], int c0, float acc[4][4]) {
#pragma unroll
  for (int k = 0; k < 32; k += 4) {
    float4 a[4], w[4];
#pragma unroll
    for (int i = 0; i < 4; ++i) a[i] = *(const float4*)&A[p0 + i][kc + k];
#pragma unroll
    for (int kk = 0; kk < 4; ++kk) w[kk] = *(const float4*)&wt[k + kk][c0];
#pragma unroll
    for (int i = 0; i < 4; ++i) {
      float ax = a[i].x, ay = a[i].y, az = a[i].z, aw_ = a[i].w;
      acc[i][0] = fmaf(ax, w[0].x, fmaf(ay, w[1].x, fmaf(az, w[2].x, fmaf(aw_, w[3].x, acc[i][0]))));
      acc[i][1] = fmaf(ax, w[0].y, fmaf(ay, w[1].y, fmaf(az, w[2].y, fmaf(aw_, w[3].y, acc[i][1]))));
      acc[i][2] = fmaf(ax, w[0].z, fmaf(ay, w[1].z, fmaf(az, w[2].z, fmaf(aw_, w[3].z, acc[i][2]))));
      acc[i][3] = fmaf(ax, w[0].w, fmaf(ay, w[1].w, fmaf(az, w[2].w, fmaf(aw_, w[3].w, acc[i][3]))));
    }
  }
}

// ---------------------------------------------------------------- stats

__global__ void k_stats_init(int* stats) {
  if (threadIdx.x == 0) {
    stats[0] = 0; stats[1] = 0;
    stats[2] = 0x7fffffff; stats[3] = IMIN;
    stats[4] = 0x7fffffff; stats[5] = IMIN;
  }
}

__global__ __launch_bounds__(256) void k_stats(const int* __restrict__ grid, int* __restrict__ stats) {
  const int2* g2 = (const int2*)grid;
  int sx = 0, sy = 0, mnx = 0x7fffffff, mxx = IMIN, mny = 0x7fffffff, mxy = IMIN;
  for (int i = blockIdx.x * 256 + threadIdx.x; i < NPTS; i += gridDim.x * 256) {
    int2 v = g2[i];
    sx += v.x; sy += v.y;
    mnx = min(mnx, v.x); mxx = max(mxx, v.x);
    mny = min(mny, v.y); mxy = max(mxy, v.y);
  }
#pragma unroll
  for (int o = 32; o >= 1; o >>= 1) {
    sx += __shfl_down(sx, o); sy += __shfl_down(sy, o);
    mnx = min(mnx, __shfl_down(mnx, o)); mxx = max(mxx, __shfl_down(mxx, o));
    mny = min(mny, __shfl_down(mny, o)); mxy = max(mxy, __shfl_down(mxy, o));
  }
  if ((threadIdx.x & 63) == 0) {
    atomicAdd(&stats[0], sx); atomicAdd(&stats[1], sy);
    atomicMin(&stats[2], mnx); atomicMax(&stats[3], mxx);
    atomicMin(&stats[4], mny); atomicMax(&stats[5], mxy);
  }
}

// ---------------------------------------------------------------- vmap + imgT

__global__ __launch_bounds__(256, 4) void k_vmap(
    const float* __restrict__ img, const float* __restrict__ val_w,
    const float* __restrict__ val_b, float* __restrict__ vmapT, float* __restrict__ imgT) {
  __shared__ float a_lds[32][68];
  __shared__ float wt[32][132];
  const int tid = threadIdx.x;
  const int p0 = blockIdx.x * 64;
  const int pg = tid >> 5, cg = tid & 31;
  float acc[8][4] = {};
#pragma unroll
  for (int kc = 0; kc < 128; kc += 32) {
#pragma unroll
    for (int i = 0; i < 8; ++i) {
      int idx = tid + i * 256;
      int k = idx >> 6, pp = idx & 63;
      a_lds[k][pp] = img[(size_t)(kc + k) * HWPX + p0 + pp];
    }
    stage_wt(wt, val_w, 128, 0, kc, tid);
    __syncthreads();
#pragma unroll
    for (int k = 0; k < 32; ++k) {
      float4 w = *(const float4*)&wt[k][cg * 4];
      float4 af0 = *(const float4*)&a_lds[k][pg * 8];
      float4 af1 = *(const float4*)&a_lds[k][pg * 8 + 4];
      float a8[8] = {af0.x, af0.y, af0.z, af0.w, af1.x, af1.y, af1.z, af1.w};
#pragma unroll
      for (int i = 0; i < 8; ++i) {
        acc[i][0] = fmaf(a8[i], w.x, acc[i][0]);
        acc[i][1] = fmaf(a8[i], w.y, acc[i][1]);
        acc[i][2] = fmaf(a8[i], w.z, acc[i][2]);
        acc[i][3] = fmaf(a8[i], w.w, acc[i][3]);
      }
    }
    // transposed image copy for the per-point channel gather
#pragma unroll
    for (int i = 0; i < 8; ++i) {
      int idx = tid + i * 256;
      int pp = idx >> 5, k = idx & 31;
      imgT[(size_t)(p0 + pp) * CC + kc + k] = a_lds[k][pp];
    }
    __syncthreads();
  }
  float4 vb = *(const float4*)&val_b[cg * 4];
  const int c = cg * 4;
  const int hh = c >> 5, d4 = c & 31;
  const int y = p0 / WIMG;
  const int xbase = p0 % WIMG + pg * 8;
#pragma unroll
  for (int i = 0; i < 8; ++i) {
    float4 o;
    o.x = acc[i][0] + vb.x; o.y = acc[i][1] + vb.y;
    o.z = acc[i][2] + vb.z; o.w = acc[i][3] + vb.w;
    *(float4*)&vmapT[(((size_t)hh * HIMG + y) * WIMG + xbase + i) * 32 + d4] = o;
  }
}

// ---------------------------------------------------------------- point stage A: query -> attn -> LN1

__global__ __launch_bounds__(256, 2) void k_point_a(
    const float* __restrict__ pf, const int* __restrict__ grid,
    const float* __restrict__ imgT, const float* __restrict__ vmapT,
    const int* __restrict__ stats,
    const float* __restrict__ pkp_w, const float* __restrict__ pkp_b,
    const float* __restrict__ pkp_s, const float* __restrict__ pkp_t,
    const float* __restrict__ fc_w, const float* __restrict__ fc_b,
    const float* __restrict__ fc_s, const float* __restrict__ fc_t,
    const float* __restrict__ off_w, const float* __restrict__ off_b,
    const float* __restrict__ aw_w, const float* __restrict__ aw_b,
    const float* __restrict__ out_w, const float* __restrict__ out_b,
    const float* __restrict__ ln1_g, const float* __restrict__ ln1_b,
    float* __restrict__ qout) {
  __shared__ float a_lds[32][132];   // pf tile, later attn_in
  __shared__ float q_lds[32][132];   // query, later x1
  __shared__ float wt[32][132];
  __shared__ float off_lds[32][32];
  __shared__ float awr[32][16];
  __shared__ int gxy[64];

  const int tid = threadIdx.x;
  const int n0 = blockIdx.x * 32;
  const int pg = tid >> 5, cg = tid & 31;

#pragma unroll
  for (int i = 0; i < 4; ++i) {
    int idx = tid + i * 256;
    int p = idx >> 5, c4 = (idx & 31) << 2;
    *(float4*)&a_lds[p][c4] = *(const float4*)&pf[(size_t)(n0 + p) * CC + c4];
  }
  if (tid < 64) gxy[tid] = grid[n0 * 2 + tid];
  __syncthreads();

  // pkp GEMM
  float acc[4][4] = {};
#pragma unroll
  for (int kc = 0; kc < 128; kc += 32) {
    stage_wt(wt, pkp_w, 128, 0, kc, tid);
    __syncthreads();
    tile_fma(a_lds, pg * 4, kc, wt, cg * 4, acc);
    __syncthreads();
  }

  const float cx = (float)stats[0] / (float)NPTS;
  const float cy = (float)stats[1] / (float)NPTS;
  const float mxx = fmaxf(fmaxf((float)stats[3] - cx, cx - (float)stats[2]), 1.0f);
  const float mxy = fmaxf(fmaxf((float)stats[5] - cy, cy - (float)stats[4]), 1.0f);

  {
    float4 pb = *(const float4*)&pkp_b[cg * 4];
    float4 ps = *(const float4*)&pkp_s[cg * 4];
    float4 pt4 = *(const float4*)&pkp_t[cg * 4];
    float4 fbb = *(const float4*)&fc_b[cg * 4];
    float4 fss = *(const float4*)&fc_s[cg * 4];
    float4 ftt = *(const float4*)&fc_t[cg * 4];
    float4 fw0 = *(const float4*)&fc_w[cg * 8];
    float4 fw1 = *(const float4*)&fc_w[cg * 8 + 4];
    float fwx[4] = {fw0.x, fw0.z, fw1.x, fw1.z};
    float fwy[4] = {fw0.y, fw0.w, fw1.y, fw1.w};
#pragma unroll
    for (int i = 0; i < 4; ++i) {
      int p = pg * 4 + i;
      int gx = gxy[p * 2], gy = gxy[p * 2 + 1];
      float rx = ((float)gx - cx) / mxx;
      float ry = ((float)gy - cy) / mxy;
      float4 ff = *(const float4*)&imgT[(size_t)(gy * WIMG + gx) * CC + cg * 4];
#pragma unroll
      for (int j = 0; j < 4; ++j) {
        float qv = (acc[i][j] + f4get(pb, j)) * f4get(ps, j) + f4get(pt4, j);
        float pos = (rx * fwx[j] + ry * fwy[j] + f4get(fbb, j)) * f4get(fss, j) + f4get(ftt, j);
        q_lds[p][cg * 4 + j] = qv + pos + f4get(ff, j);
      }
    }
  }
  __syncthreads();

  // off (32) + aw (16) heads
  {
    int p = tid >> 3, g = tid & 7;
    float accO[4] = {}; float accA[2] = {};
    const float* qrow = q_lds[p];
#pragma unroll 8
    for (int k = 0; k < 128; k += 4) {
      float4 qv = *(const float4*)&qrow[k];
#pragma unroll
      for (int r = 0; r < 4; ++r) {
        float4 w = *(const float4*)&off_w[(size_t)(g * 4 + r) * 128 + k];
        accO[r] = fmaf(qv.x, w.x, fmaf(qv.y, w.y, fmaf(qv.z, w.z, fmaf(qv.w, w.w, accO[r]))));
      }
#pragma unroll
      for (int r = 0; r < 2; ++r) {
        float4 w = *(const float4*)&aw_w[(size_t)(g * 2 + r) * 128 + k];
        accA[r] = fmaf(qv.x, w.x, fmaf(qv.y, w.y, fmaf(qv.z, w.z, fmaf(qv.w, w.w, accA[r]))));
      }
    }
#pragma unroll
    for (int r = 0; r < 4; ++r) off_lds[p][g * 4 + r] = accO[r] + off_b[g * 4 + r];
#pragma unroll
    for (int r = 0; r < 2; ++r) awr[p][g * 2 + r] = accA[r] + aw_b[g * 2 + r];
  }
  __syncthreads();

  // softmax + bilinear sampling (thread = one (p, h) pair, one 16-ch half)
  {
    int pr = tid >> 1, half = tid & 1;
    int p = pr >> 2, h = pr & 3;
    float w0 = awr[p][h * 4 + 0], w1 = awr[p][h * 4 + 1];
    float w2 = awr[p][h * 4 + 2], w3 = awr[p][h * 4 + 3];
    float m = fmaxf(fmaxf(w0, w1), fmaxf(w2, w3));
    float e0 = expf(w0 - m), e1 = expf(w1 - m), e2 = expf(w2 - m), e3 = expf(w3 - m);
    float inv = 1.0f / (e0 + e1 + e2 + e3);
    float awn[4] = {e0 * inv, e1 * inv, e2 * inv, e3 * inv};
    float gxf = (float)gxy[p * 2], gyf = (float)gxy[p * 2 + 1];
    float accd[16] = {};
    const float* vbase = vmapT + (size_t)h * HIMG * WIMG * 32 + half * 16;
#pragma unroll
    for (int np = 0; np < 4; ++np) {
      float ox = off_lds[p][(h * 4 + np) * 2 + 0];
      float oy = off_lds[p][(h * 4 + np) * 2 + 1];
      float lx = (gxf + 0.5f) * (1.0f / WIMG) + ox * (1.0f / WIMG);
      float ly = (gyf + 0.5f) * (1.0f / HIMG) + oy * (1.0f / HIMG);
      float px = lx * (float)WIMG - 0.5f;
      float py = ly * (float)HIMG - 0.5f;
      float x0f = floorf(px), y0f = floorf(py);
      float dx = px - x0f, dy = py - y0f;
      float x1f = x0f + 1.0f, y1f = y0f + 1.0f;
      bool vx0 = (x0f >= 0.f) && (x0f < (float)WIMG);
      bool vx1 = (x1f >= 0.f) && (x1f < (float)WIMG);
      bool vy0 = (y0f >= 0.f) && (y0f < (float)HIMG);
      bool vy1 = (y1f >= 0.f) && (y1f < (float)HIMG);
      int x0c = (int)fminf(fmaxf(x0f, 0.f), (float)(WIMG - 1));
      int x1c = (int)fminf(fmaxf(x1f, 0.f), (float)(WIMG - 1));
      int y0c = (int)fminf(fmaxf(y0f, 0.f), (float)(HIMG - 1));
      int y1c = (int)fminf(fmaxf(y1f, 0.f), (float)(HIMG - 1));
      float a = awn[np];
      float c00 = (vx0 && vy0) ? a * (1.f - dx) * (1.f - dy) : 0.f;
      float c01 = (vx1 && vy0) ? a * dx * (1.f - dy) : 0.f;
      float c10 = (vx0 && vy1) ? a * (1.f - dx) * dy : 0.f;
      float c11 = (vx1 && vy1) ? a * dx * dy : 0.f;
      const float* p00 = vbase + ((size_t)y0c * WIMG + x0c) * 32;
      const float* p01 = vbase + ((size_t)y0c * WIMG + x1c) * 32;
      const float* p10 = vbase + ((size_t)y1c * WIMG + x0c) * 32;
      const float* p11 = vbase + ((size_t)y1c * WIMG + x1c) * 32;
#pragma unroll
      for (int q4 = 0; q4 < 4; ++q4) {
        float4 v00 = *(const float4*)&p00[q4 * 4];
        float4 v01 = *(const float4*)&p01[q4 * 4];
        float4 v10 = *(const float4*)&p10[q4 * 4];
        float4 v11 = *(const float4*)&p11[q4 * 4];
        accd[q4 * 4 + 0] = fmaf(c00, v00.x, fmaf(c01, v01.x, fmaf(c10, v10.x, fmaf(c11, v11.x, accd[q4 * 4 + 0]))));
        accd[q4 * 4 + 1] = fmaf(c00, v00.y, fmaf(c01, v01.y, fmaf(c10, v10.y, fmaf(c11, v11.y, accd[q4 * 4 + 1]))));
        accd[q4 * 4 + 2] = fmaf(c00, v00.z, fmaf(c01, v01.z, fmaf(c10, v10.z, fmaf(c11, v11.z, accd[q4 * 4 + 2]))));
        accd[q4 * 4 + 3] = fmaf(c00, v00.w, fmaf(c01, v01.w, fmaf(c10, v10.w, fmaf(c11, v11.w, accd[q4 * 4 + 3]))));
      }
    }
#pragma unroll
    for (int q4 = 0; q4 < 4; ++q4) {
      *(float4*)&a_lds[p][h * 32 + half * 16 + q4 * 4] =
          make_float4(accd[q4 * 4 + 0], accd[q4 * 4 + 1], accd[q4 * 4 + 2], accd[q4 * 4 + 3]);
    }
  }
  __syncthreads();

  // out projection + residual
  float acc2[4][4] = {};
#pragma unroll
  for (int kc = 0; kc < 128; kc += 32) {
    stage_wt(wt, out_w, 128, 0, kc, tid);
    __syncthreads();
    tile_fma(a_lds, pg * 4, kc, wt, cg * 4, acc2);
    __syncthreads();
  }
  {
    float4 ob = *(const float4*)&out_b[cg * 4];
#pragma unroll
    for (int i = 0; i < 4; ++i) {
      int p = pg * 4 + i;
#pragma unroll
      for (int j = 0; j < 4; ++j)
        q_lds[p][cg * 4 + j] += acc2[i][j] + f4get(ob, j);
    }
  }
  __syncthreads();

  // LN1 -> qout
  {
    int p = tid >> 3, l = tid & 7, c0 = l * 16;
    float v[16];
#pragma unroll
    for (int q4 = 0; q4 < 4; ++q4) {
      float4 t = *(const float4*)&q_lds[p][c0 + q4 * 4];
      v[q4 * 4 + 0] = t.x; v[q4 * 4 + 1] = t.y; v[q4 * 4 + 2] = t.z; v[q4 * 4 + 3] = t.w;
    }
    float s = 0.f, ss = 0.f;
#pragma unroll
    for (int i = 0; i < 16; ++i) { s += v[i]; ss += v[i] * v[i]; }
#pragma unroll
    for (int mm = 1; mm <= 4; mm <<= 1) { s += __shfl_xor(s, mm); ss += __shfl_xor(ss, mm); }
    float mu = s * (1.0f / 128.0f);
    float var = ss * (1.0f / 128.0f) - mu * mu;
    float rstd = rsqrtf(var + 1e-5f);
#pragma unroll
    for (int q4 = 0; q4 < 4; ++q4) {
      int c = c0 + q4 * 4;
      float4 g = *(const float4*)&ln1_g[c];
      float4 b = *(const float4*)&ln1_b[c];
      float4 o;
      o.x = (v[q4 * 4 + 0] - mu) * rstd * g.x + b.x;
      o.y = (v[q4 * 4 + 1] - mu) * rstd * g.y + b.y;
      o.z = (v[q4 * 4 + 2] - mu) * rstd * g.z + b.z;
      o.w = (v[q4 * 4 + 3] - mu) * rstd * g.w + b.w;
      *(float4*)&qout[(size_t)(n0 + p) * CC + c] = o;
    }
  }
}

// ---------------------------------------------------------------- FFN + LN2 (in place on q)

__global__ __launch_bounds__(256, 3) void k_ffn(
    float* __restrict__ qio, const float* __restrict__ w1, const float* __restrict__ b1,
    const float* __restrict__ w2, const float* __restrict__ b2,
    const float* __restrict__ g2, const float* __restrict__ bb2) {
  __shared__ float q_lds[32][132];
  __shared__ float h_lds[32][132];
  __shared__ float wt[32][132];
  const int tid = threadIdx.x;
  const int n0 = blockIdx.x * 32;
  const int pg = tid >> 5, cg = tid & 31;
#pragma unroll
  for (int i = 0; i < 4; ++i) {
    int idx = tid + i * 256;
    int p = idx >> 5, c4 = (idx & 31) << 2;
    *(float4*)&q_lds[p][c4] = *(const float4*)&qio[(size_t)(n0 + p) * CC + c4];
  }
  __syncthreads();
  float acc[4][4] = {};
#pragma unroll
  for (int jc = 0; jc < 4; ++jc) {
    float acc2[4][4] = {};
#pragma unroll
    for (int kc = 0; kc < 128; kc += 32) {
      stage_wt(wt, w1, 128, jc * 128, kc, tid);
      __syncthreads();
      tile_fma(q_lds, pg * 4, kc, wt, cg * 4, acc2);
      __syncthreads();
    }
    float4 bb = *(const float4*)&b1[jc * 128 + cg * 4];
#pragma unroll
    for (int i = 0; i < 4; ++i)
#pragma unroll
      for (int j = 0; j < 4; ++j)
        h_lds[pg * 4 + i][cg * 4 + j] = fmaxf(acc2[i][j] + f4get(bb, j), 0.f);
    __syncthreads();
#pragma unroll
    for (int kc = 0; kc < 128; kc += 32) {
      stage_wt(wt, w2, 512, 0, jc * 128 + kc, tid);
      __syncthreads();
      tile_fma(h_lds, pg * 4, kc, wt, cg * 4, acc);
      __syncthreads();
    }
  }
  {
    float4 b2v = *(const float4*)&b2[cg * 4];
#pragma unroll
    for (int i = 0; i < 4; ++i)
#pragma unroll
      for (int j = 0; j < 4; ++j)
        h_lds[pg * 4 + i][cg * 4 + j] = q_lds[pg * 4 + i][cg * 4 + j] + acc[i][j] + f4get(b2v, j);
  }
  __syncthreads();
  {
    int p = tid >> 3, l = tid & 7, c0 = l * 16;
    float v[16];
#pragma unroll
    for (int q4 = 0; q4 < 4; ++q4) {
      float4 t = *(const float4*)&h_lds[p][c0 + q4 * 4];
      v[q4 * 4 + 0] = t.x; v[q4 * 4 + 1] = t.y; v[q4 * 4 + 2] = t.z; v[q4 * 4 + 3] = t.w;
    }
    float s = 0.f, ss = 0.f;
#pragma unroll
    for (int i = 0; i < 16; ++i) { s += v[i]; ss += v[i] * v[i]; }
#pragma unroll
    for (int mm = 1; mm <= 4; mm <<= 1) { s += __shfl_xor(s, mm); ss += __shfl_xor(ss, mm); }
    float mu = s * (1.0f / 128.0f);
    float var = ss * (1.0f / 128.0f) - mu * mu;
    float rstd = rsqrtf(var + 1e-5f);
#pragma unroll
    for (int q4 = 0; q4 < 4; ++q4) {
      int c = c0 + q4 * 4;
      float4 g = *(const float4*)&g2[c];
      float4 b = *(const float4*)&bb2[c];
      float4 o;
      o.x = (v[q4 * 4 + 0] - mu) * rstd * g.x + b.x;
      o.y = (v[q4 * 4 + 1] - mu) * rstd * g.y + b.y;
      o.z = (v[q4 * 4 + 2] - mu) * rstd * g.z + b.z;
      o.w = (v[q4 * 4 + 3] - mu) * rstd * g.w + b.w;
      *(float4*)&qio[(size_t)(n0 + p) * CC + c] = o;
    }
  }
}

// ---------------------------------------------------------------- final fuse

__global__ __launch_bounds__(256, 3) void k_final(
    const float* __restrict__ pf, const float* __restrict__ q,
    const float* __restrict__ pt_w, const float* __restrict__ pt_b,
    const float* __restrict__ pt_s, const float* __restrict__ pt_t,
    const float* __restrict__ fuse_w, const float* __restrict__ fuse_b,
    const float* __restrict__ fuse_s, const float* __restrict__ fuse_t,
    float* __restrict__ outp) {
  __shared__ float a_lds[32][132];   // pf tile, then relu(pts_pre)
  __shared__ float q_lds[32][132];   // relu(q)
  __shared__ float wt[32][132];
  const int tid = threadIdx.x;
  const int n0 = blockIdx.x * 32;
  const int pg = tid >> 5, cg = tid & 31;
#pragma unroll
  for (int i = 0; i < 4; ++i) {
    int idx = tid + i * 256;
    int p = idx >> 5, c4 = (idx & 31) << 2;
    *(float4*)&a_lds[p][c4] = *(const float4*)&pf[(size_t)(n0 + p) * CC + c4];
    float4 qq = *(const float4*)&q[(size_t)(n0 + p) * CC + c4];
    qq.x = fmaxf(qq.x, 0.f); qq.y = fmaxf(qq.y, 0.f);
    qq.z = fmaxf(qq.z, 0.f); qq.w = fmaxf(qq.w, 0.f);
    *(float4*)&q_lds[p][c4] = qq;
  }
  __syncthreads();
  float accP[4][4] = {};
#pragma unroll
  for (int kc = 0; kc < 128; kc += 32) {
    stage_wt(wt, pt_w, 128, 0, kc, tid);
    __syncthreads();
    tile_fma(a_lds, pg * 4, kc, wt, cg * 4, accP);
    __syncthreads();
  }
  {
    float4 pb = *(const float4*)&pt_b[cg * 4];
    float4 ps = *(const float4*)&pt_s[cg * 4];
    float4 pt4 = *(const float4*)&pt_t[cg * 4];
#pragma unroll
    for (int i = 0; i < 4; ++i)
#pragma unroll
      for (int j = 0; j < 4; ++j)
        a_lds[pg * 4 + i][cg * 4 + j] =
            fmaxf((accP[i][j] + f4get(pb, j)) * f4get(ps, j) + f4get(pt4, j), 0.f);
  }
  __syncthreads();
  float acc[4][4] = {};
#pragma unroll
  for (int kc = 0; kc < 128; kc += 32) {
    stage_wt(wt, fuse_w, 256, 0, kc, tid);
    __syncthreads();
    tile_fma(a_lds, pg * 4, kc, wt, cg * 4, acc);
    __syncthreads();
  }
#pragma unroll
  for (int kc = 0; kc < 128; kc += 32) {
    stage_wt(wt, fuse_w, 256, 0, 128 + kc, tid);
    __syncthreads();
    tile_fma(q_lds, pg * 4, kc, wt, cg * 4, acc);
    __syncthreads();
  }
  {
    float4 fb = *(const float4*)&fuse_b[cg * 4];
    float4 fs = *(const float4*)&fuse_s[cg * 4];
    float4 ft = *(const float4*)&fuse_t[cg * 4];
#pragma unroll
    for (int i = 0; i < 4; ++i) {
      float4 o;
      o.x = fmaxf((acc[i][0] + fb.x) * fs.x + ft.x, 0.f);
      o.y = fmaxf((acc[i][1] + fb.y) * fs.y + ft.y, 0.f);
      o.z = fmaxf((acc[i][2] + fb.z) * fs.z + ft.z, 0.f);
      o.w = fmaxf((acc[i][3] + fb.w) * fs.w + ft.w, 0.f);
      *(float4*)&outp[(size_t)(n0 + pg * 4 + i) * CC + cg * 4] = o;
    }
  }
}

// ---------------------------------------------------------------- launch

extern "C" void kernel_launch(void* const* d_in, const int* in_sizes, int n_in,
                              void* d_out, int out_size, void* d_ws, size_t ws_size,
                              hipStream_t stream) {
  const float* pf    = (const float*)d_in[0];
  const float* img   = (const float*)d_in[1];
  const int*   grid  = (const int*)d_in[2];
  const float* pkp_w = (const float*)d_in[3];
  const float* pkp_b = (const float*)d_in[4];
  const float* pkp_s = (const float*)d_in[5];
  const float* pkp_t = (const float*)d_in[6];
  const float* fc_w  = (const float*)d_in[7];
  const float* fc_b  = (const float*)d_in[8];
  const float* fc_s  = (const float*)d_in[9];
  const float* fc_t  = (const float*)d_in[10];
  const float* pt_w  = (const float*)d_in[11];
  const float* pt_b  = (const float*)d_in[12];
  const float* pt_s  = (const float*)d_in[13];
  const float* pt_t  = (const float*)d_in[14];
  const float* val_w = (const float*)d_in[15];
  const float* val_b = (const float*)d_in[16];
  const float* off_w = (const float*)d_in[17];
  const float* off_b = (const float*)d_in[18];
  const float* aw_w  = (const float*)d_in[19];
  const float* aw_b  = (const float*)d_in[20];
  const float* out_w = (const float*)d_in[21];
  const float* out_b = (const float*)d_in[22];
  const float* ln1_g = (const float*)d_in[23];
  const float* ln1_b = (const float*)d_in[24];
  const float* ffn_w1 = (const float*)d_in[25];
  const float* ffn_b1 = (const float*)d_in[26];
  const float* ffn_w2 = (const float*)d_in[27];
  const float* ffn_b2 = (const float*)d_in[28];
  const float* ln2_g = (const float*)d_in[29];
  const float* ln2_b = (const float*)d_in[30];
  const float* fuse_w = (const float*)d_in[31];
  const float* fuse_b = (const float*)d_in[32];
  const float* fuse_s = (const float*)d_in[33];
  const float* fuse_t = (const float*)d_in[34];
  float* outp = (float*)d_out;

  char* ws = (char*)d_ws;
  int* stats   = (int*)ws;
  float* vmapT = (float*)(ws + 256);
  float* imgT  = vmapT + (size_t)4 * HIMG * WIMG * 32;   // 15,728,640 floats
  float* qbuf  = imgT + (size_t)HWPX * CC;               // 15,728,640 floats

  k_stats_init<<<1, 64, 0, stream>>>(stats);
  k_stats<<<256, 256, 0, stream>>>(grid, stats);
  k_vmap<<<HWPX / 64, 256, 0, stream>>>(img, val_w, val_b, vmapT, imgT);
  k_point_a<<<NPTS / 32, 256, 0, stream>>>(pf, grid, imgT, vmapT, stats,
                                           pkp_w, pkp_b, pkp_s, pkp_t,
                                           fc_w, fc_b, fc_s, fc_t,
                                           off_w, off_b, aw_w, aw_b,
                                           out_w, out_b, ln1_g, ln1_b, qbuf);
  k_ffn<<<NPTS / 32, 256, 0, stream>>>(qbuf, ffn_w1, ffn_b1, ffn_w2, ffn_b2, ln2_g, ln2_b);
  k_final<<<NPTS / 32, 256, 0, stream>>>(pf, qbuf, pt_w, pt_b, pt_s, pt_t,
                                         fuse_w, fuse_b, fuse_s, fuse_t, outp);
}

// Round 2
// 1834.791 us; speedup vs baseline: 1.1007x; 1.1007x over previous
//
#include <hip/hip_runtime.h>
#include <hip/hip_bf16.h>
#include <hip/hip_fp16.h>

#define NPTS 120000
#define CC   128
#define HIMG 192
#define WIMG 640
#define HWPX (HIMG * WIMG)
#define IMIN (-2147483647 - 1)

// ---------------------------------------------------------------- helpers

__device__ __forceinline__ float f4get(const float4& v, int j) {
  switch (j) { case 0: return v.x; case 1: return v.y; case 2: return v.z; default: return v.w; }
}

// stage transposed weight chunk: wt[k][c] = W[(rowbase+c)*rowlen + kc + k], k<32, c<128
__device__ __forceinline__ void stage_wt(float (*wt)[132], const float* __restrict__ W,
                                         int rowlen, int rowbase, int kc, int tid) {
#pragma unroll
  for (int i = 0; i < 16; ++i) {
    int idx = tid + i * 256;
    int c = idx >> 5, k = idx & 31;
    wt[k][c] = W[(size_t)(rowbase + c) * rowlen + kc + k];
  }
}

// acc[i][j] += sum_{k<32} A[p0+i][kc+k] * wt[k][c0+j]
__device__ __forceinline__ void tile_fma(const float (*A)[132], int p0, int kc,
                                         const float (*wt)[132], int c0, float acc[4][4]) {
#pragma unroll
  for (int k = 0; k < 32; k += 4) {
    float4 a[4], w[4];
#pragma unroll
    for (int i = 0; i < 4; ++i) a[i] = *(const float4*)&A[p0 + i][kc + k];
#pragma unroll
    for (int kk = 0; kk < 4; ++kk) w[kk] = *(const float4*)&wt[k + kk][c0];
#pragma unroll
    for (int i = 0; i < 4; ++i) {
      float ax = a[i].x, ay = a[i].y, az = a[i].z, aw_ = a[i].w;
      acc[i][0] = fmaf(ax, w[0].x, fmaf(ay, w[1].x, fmaf(az, w[2].x, fmaf(aw_, w[3].x, acc[i][0]))));
      acc[i][1] = fmaf(ax, w[0].y, fmaf(ay, w[1].y, fmaf(az, w[2].y, fmaf(aw_, w[3].y, acc[i][1]))));
      acc[i][2] = fmaf(ax, w[0].z, fmaf(ay, w[1].z, fmaf(az, w[2].z, fmaf(aw_, w[3].z, acc[i][2]))));
      acc[i][3] = fmaf(ax, w[0].w, fmaf(ay, w[1].w, fmaf(az, w[2].w, fmaf(aw_, w[3].w, acc[i][3]))));
    }
  }
}

// ---------------------------------------------------------------- stats

__global__ void k_stats_init(int* stats) {
  if (threadIdx.x == 0) {
    stats[0] = 0; stats[1] = 0;
    stats[2] = 0x7fffffff; stats[3] = IMIN;
    stats[4] = 0x7fffffff; stats[5] = IMIN;
  }
}

__global__ __launch_bounds__(256) void k_stats(const int* __restrict__ grid, int* __restrict__ stats) {
  const int2* g2 = (const int2*)grid;
  int sx = 0, sy = 0, mnx = 0x7fffffff, mxx = IMIN, mny = 0x7fffffff, mxy = IMIN;
  for (int i = blockIdx.x * 256 + threadIdx.x; i < NPTS; i += gridDim.x * 256) {
    int2 v = g2[i];
    sx += v.x; sy += v.y;
    mnx = min(mnx, v.x); mxx = max(mxx, v.x);
    mny = min(mny, v.y); mxy = max(mxy, v.y);
  }
#pragma unroll
  for (int o = 32; o >= 1; o >>= 1) {
    sx += __shfl_down(sx, o); sy += __shfl_down(sy, o);
    mnx = min(mnx, __shfl_down(mnx, o)); mxx = max(mxx, __shfl_down(mxx, o));
    mny = min(mny, __shfl_down(mny, o)); mxy = max(mxy, __shfl_down(mxy, o));
  }
  if ((threadIdx.x & 63) == 0) {
    atomicAdd(&stats[0], sx); atomicAdd(&stats[1], sy);
    atomicMin(&stats[2], mnx); atomicMax(&stats[3], mxx);
    atomicMin(&stats[4], mny); atomicMax(&stats[5], mxy);
  }
}

// ---------------------------------------------------------------- vmap (fp16) + imgT

__global__ __launch_bounds__(256, 4) void k_vmap(
    const float* __restrict__ img, const float* __restrict__ val_w,
    const float* __restrict__ val_b, __half* __restrict__ vmapT, float* __restrict__ imgT) {
  __shared__ float a_lds[32][68];
  __shared__ float wt[32][132];
  const int tid = threadIdx.x;
  const int p0 = blockIdx.x * 64;
  const int pg = tid >> 5, cg = tid & 31;
  float acc[8][4] = {};
#pragma unroll
  for (int kc = 0; kc < 128; kc += 32) {
#pragma unroll
    for (int i = 0; i < 8; ++i) {
      int idx = tid + i * 256;
      int k = idx >> 6, pp = idx & 63;
      a_lds[k][pp] = img[(size_t)(kc + k) * HWPX + p0 + pp];
    }
    stage_wt(wt, val_w, 128, 0, kc, tid);
    __syncthreads();
#pragma unroll
    for (int k = 0; k < 32; ++k) {
      float4 w = *(const float4*)&wt[k][cg * 4];
      float4 af0 = *(const float4*)&a_lds[k][pg * 8];
      float4 af1 = *(const float4*)&a_lds[k][pg * 8 + 4];
      float a8[8] = {af0.x, af0.y, af0.z, af0.w, af1.x, af1.y, af1.z, af1.w};
#pragma unroll
      for (int i = 0; i < 8; ++i) {
        acc[i][0] = fmaf(a8[i], w.x, acc[i][0]);
        acc[i][1] = fmaf(a8[i], w.y, acc[i][1]);
        acc[i][2] = fmaf(a8[i], w.z, acc[i][2]);
        acc[i][3] = fmaf(a8[i], w.w, acc[i][3]);
      }
    }
    // transposed image copy for the per-point channel gather
#pragma unroll
    for (int i = 0; i < 8; ++i) {
      int idx = tid + i * 256;
      int pp = idx >> 5, k = idx & 31;
      imgT[(size_t)(p0 + pp) * CC + kc + k] = a_lds[k][pp];
    }
    __syncthreads();
  }
  float4 vb = *(const float4*)&val_b[cg * 4];
  const int c = cg * 4;
  const int hh = c >> 5, d4 = c & 31;
  const int y = p0 / WIMG;
  const int xbase = p0 % WIMG + pg * 8;
#pragma unroll
  for (int i = 0; i < 8; ++i) {
    union { __half2 h2[2]; float2 f2; } pk;
    pk.h2[0] = __floats2half2_rn(acc[i][0] + vb.x, acc[i][1] + vb.y);
    pk.h2[1] = __floats2half2_rn(acc[i][2] + vb.z, acc[i][3] + vb.w);
    *(float2*)&vmapT[(((size_t)hh * HIMG + y) * WIMG + xbase + i) * 32 + d4] = pk.f2;
  }
}

// ---------------------------------------------------------------- query: pkp GEMM + pos + fuse, off/aw heads

__global__ __launch_bounds__(256, 3) void k_query(
    const float* __restrict__ pf, const int* __restrict__ grid,
    const float* __restrict__ imgT, const int* __restrict__ stats,
    const float* __restrict__ pkp_w, const float* __restrict__ pkp_b,
    const float* __restrict__ pkp_s, const float* __restrict__ pkp_t,
    const float* __restrict__ fc_w, const float* __restrict__ fc_b,
    const float* __restrict__ fc_s, const float* __restrict__ fc_t,
    const float* __restrict__ off_w, const float* __restrict__ off_b,
    const float* __restrict__ aw_w, const float* __restrict__ aw_b,
    float* __restrict__ qout, float* __restrict__ pxyb, float* __restrict__ awb) {
  __shared__ float a_lds[32][132];   // pf tile
  __shared__ float q_lds[32][132];   // query
  __shared__ float wt[32][132];
  __shared__ float awr[32][16];
  __shared__ int gxy[64];

  const int tid = threadIdx.x;
  const int n0 = blockIdx.x * 32;
  const int pg = tid >> 5, cg = tid & 31;

#pragma unroll
  for (int i = 0; i < 4; ++i) {
    int idx = tid + i * 256;
    int p = idx >> 5, c4 = (idx & 31) << 2;
    *(float4*)&a_lds[p][c4] = *(const float4*)&pf[(size_t)(n0 + p) * CC + c4];
  }
  if (tid < 64) gxy[tid] = grid[n0 * 2 + tid];
  __syncthreads();

  // pkp GEMM
  float acc[4][4] = {};
#pragma unroll
  for (int kc = 0; kc < 128; kc += 32) {
    stage_wt(wt, pkp_w, 128, 0, kc, tid);
    __syncthreads();
    tile_fma(a_lds, pg * 4, kc, wt, cg * 4, acc);
    __syncthreads();
  }

  const float cx = (float)stats[0] / (float)NPTS;
  const float cy = (float)stats[1] / (float)NPTS;
  const float mxx = fmaxf(fmaxf((float)stats[3] - cx, cx - (float)stats[2]), 1.0f);
  const float mxy = fmaxf(fmaxf((float)stats[5] - cy, cy - (float)stats[4]), 1.0f);

  {
    float4 pb = *(const float4*)&pkp_b[cg * 4];
    float4 ps = *(const float4*)&pkp_s[cg * 4];
    float4 pt4 = *(const float4*)&pkp_t[cg * 4];
    float4 fbb = *(const float4*)&fc_b[cg * 4];
    float4 fss = *(const float4*)&fc_s[cg * 4];
    float4 ftt = *(const float4*)&fc_t[cg * 4];
    float4 fw0 = *(const float4*)&fc_w[cg * 8];
    float4 fw1 = *(const float4*)&fc_w[cg * 8 + 4];
    float fwx[4] = {fw0.x, fw0.z, fw1.x, fw1.z};
    float fwy[4] = {fw0.y, fw0.w, fw1.y, fw1.w};
#pragma unroll
    for (int i = 0; i < 4; ++i) {
      int p = pg * 4 + i;
      int gx = gxy[p * 2], gy = gxy[p * 2 + 1];
      float rx = ((float)gx - cx) / mxx;
      float ry = ((float)gy - cy) / mxy;
      float4 ff = *(const float4*)&imgT[(size_t)(gy * WIMG + gx) * CC + cg * 4];
#pragma unroll
      for (int j = 0; j < 4; ++j) {
        float qv = (acc[i][j] + f4get(pb, j)) * f4get(ps, j) + f4get(pt4, j);
        float pos = (rx * fwx[j] + ry * fwy[j] + f4get(fbb, j)) * f4get(fss, j) + f4get(ftt, j);
        q_lds[p][cg * 4 + j] = qv + pos + f4get(ff, j);
      }
    }
  }
  __syncthreads();

  // off (32) + aw (16) heads; px = gx + off_x, py = gy + off_y (exact algebraic reduction)
  {
    int p = tid >> 3, g = tid & 7;
    float accO[4] = {}; float accA[2] = {};
    const float* qrow = q_lds[p];
#pragma unroll 8
    for (int k = 0; k < 128; k += 4) {
      float4 qv = *(const float4*)&qrow[k];
#pragma unroll
      for (int r = 0; r < 4; ++r) {
        float4 w = *(const float4*)&off_w[(size_t)(g * 4 + r) * 128 + k];
        accO[r] = fmaf(qv.x, w.x, fmaf(qv.y, w.y, fmaf(qv.z, w.z, fmaf(qv.w, w.w, accO[r]))));
      }
#pragma unroll
      for (int r = 0; r < 2; ++r) {
        float4 w = *(const float4*)&aw_w[(size_t)(g * 2 + r) * 128 + k];
        accA[r] = fmaf(qv.x, w.x, fmaf(qv.y, w.y, fmaf(qv.z, w.z, fmaf(qv.w, w.w, accA[r]))));
      }
    }
    float gxf = (float)gxy[p * 2], gyf = (float)gxy[p * 2 + 1];
    float4 o;
    o.x = accO[0] + off_b[g * 4 + 0] + gxf;
    o.y = accO[1] + off_b[g * 4 + 1] + gyf;
    o.z = accO[2] + off_b[g * 4 + 2] + gxf;
    o.w = accO[3] + off_b[g * 4 + 3] + gyf;
    *(float4*)&pxyb[(size_t)(n0 + p) * 32 + g * 4] = o;
#pragma unroll
    for (int r = 0; r < 2; ++r) awr[p][g * 2 + r] = accA[r] + aw_b[g * 2 + r];
  }
  __syncthreads();

  // softmax over NP=4 -> awb
  if (tid < 128) {
    int p = tid >> 2, h = tid & 3;
    float w0 = awr[p][h * 4 + 0], w1 = awr[p][h * 4 + 1];
    float w2 = awr[p][h * 4 + 2], w3 = awr[p][h * 4 + 3];
    float m = fmaxf(fmaxf(w0, w1), fmaxf(w2, w3));
    float e0 = expf(w0 - m), e1 = expf(w1 - m), e2 = expf(w2 - m), e3 = expf(w3 - m);
    float inv = 1.0f / (e0 + e1 + e2 + e3);
    *(float4*)&awb[(size_t)(n0 + p) * 16 + h * 4] =
        make_float4(e0 * inv, e1 * inv, e2 * inv, e3 * inv);
  }

  // query -> qout
#pragma unroll
  for (int i = 0; i < 4; ++i) {
    int idx = tid + i * 256;
    int p = idx >> 5, c4 = (idx & 31) << 2;
    *(float4*)&qout[(size_t)(n0 + p) * CC + c4] = *(const float4*)&q_lds[p][c4];
  }
}

// ---------------------------------------------------------------- pure gather kernel (high TLP)

__global__ __launch_bounds__(256, 5) void k_sample(
    const float* __restrict__ pxyb, const float* __restrict__ awb,
    const __half* __restrict__ vmapT, float* __restrict__ sbuf) {
  const int gid = blockIdx.x * 256 + threadIdx.x;   // (p, h, half16)
  const int half = gid & 1, h = (gid >> 1) & 3, p = gid >> 3;
  const float4* pxr = (const float4*)(pxyb + (size_t)p * 32 + h * 8);
  float4 pa = pxr[0], pb = pxr[1];
  float4 awv = *(const float4*)(awb + (size_t)p * 16 + h * 4);
  float pxs[4] = {pa.x, pa.z, pb.x, pb.z};
  float pys[4] = {pa.y, pa.w, pb.y, pb.w};
  float aws[4] = {awv.x, awv.y, awv.z, awv.w};
  float accd[16] = {};
  const __half* vbase = vmapT + (size_t)h * HWPX * 32 + half * 16;
#pragma unroll
  for (int np = 0; np < 4; ++np) {
    float px = pxs[np], py = pys[np];
    float x0f = floorf(px), y0f = floorf(py);
    float dx = px - x0f, dy = py - y0f;
    float x1f = x0f + 1.0f, y1f = y0f + 1.0f;
    bool vx0 = (x0f >= 0.f) && (x0f < (float)WIMG);
    bool vx1 = (x1f >= 0.f) && (x1f < (float)WIMG);
    bool vy0 = (y0f >= 0.f) && (y0f < (float)HIMG);
    bool vy1 = (y1f >= 0.f) && (y1f < (float)HIMG);
    int x0c = (int)fminf(fmaxf(x0f, 0.f), (float)(WIMG - 1));
    int x1c = (int)fminf(fmaxf(x1f, 0.f), (float)(WIMG - 1));
    int y0c = (int)fminf(fmaxf(y0f, 0.f), (float)(HIMG - 1));
    int y1c = (int)fminf(fmaxf(y1f, 0.f), (float)(HIMG - 1));
    float a = aws[np];
    float c00 = (vx0 && vy0) ? a * (1.f - dx) * (1.f - dy) : 0.f;
    float c01 = (vx1 && vy0) ? a * dx * (1.f - dy) : 0.f;
    float c10 = (vx0 && vy1) ? a * (1.f - dx) * dy : 0.f;
    float c11 = (vx1 && vy1) ? a * dx * dy : 0.f;
    const float4* t00 = (const float4*)(vbase + (size_t)(y0c * WIMG + x0c) * 32);
    const float4* t01 = (const float4*)(vbase + (size_t)(y0c * WIMG + x1c) * 32);
    const float4* t10 = (const float4*)(vbase + (size_t)(y1c * WIMG + x0c) * 32);
    const float4* t11 = (const float4*)(vbase + (size_t)(y1c * WIMG + x1c) * 32);
#pragma unroll
    for (int qq = 0; qq < 2; ++qq) {
      union U { float4 f; __half2 h2[4]; };
      U u00, u01, u10, u11;
      u00.f = t00[qq]; u01.f = t01[qq]; u10.f = t10[qq]; u11.f = t11[qq];
#pragma unroll
      for (int j = 0; j < 4; ++j) {
        float2 w00 = __half22float2(u00.h2[j]);
        float2 w01 = __half22float2(u01.h2[j]);
        float2 w10 = __half22float2(u10.h2[j]);
        float2 w11 = __half22float2(u11.h2[j]);
        int c = qq * 8 + j * 2;
        accd[c]     = fmaf(c00, w00.x, fmaf(c01, w01.x, fmaf(c10, w10.x, fmaf(c11, w11.x, accd[c]))));
        accd[c + 1] = fmaf(c00, w00.y, fmaf(c01, w01.y, fmaf(c10, w10.y, fmaf(c11, w11.y, accd[c + 1]))));
      }
    }
  }
  float* out = sbuf + (size_t)p * CC + h * 32 + half * 16;
#pragma unroll
  for (int q4 = 0; q4 < 4; ++q4)
    *(float4*)(out + q4 * 4) =
        make_float4(accd[q4 * 4 + 0], accd[q4 * 4 + 1], accd[q4 * 4 + 2], accd[q4 * 4 + 3]);
}

// ---------------------------------------------------------------- outproj + LN1 + FFN + LN2

__global__ __launch_bounds__(256, 3) void k_ffn2(
    const float* __restrict__ sbuf, float* __restrict__ qio,
    const float* __restrict__ out_w, const float* __restrict__ out_b,
    const float* __restrict__ ln1_g, const float* __restrict__ ln1_b,
    const float* __restrict__ w1, const float* __restrict__ b1,
    const float* __restrict__ w2, const float* __restrict__ b2,
    const float* __restrict__ g2, const float* __restrict__ bb2) {
  __shared__ float a_lds[32][132];   // sbuf tile, later hidden chunks
  __shared__ float q_lds[32][132];   // query + attn residual -> x1 (post LN1)
  __shared__ float wt[32][132];
  const int tid = threadIdx.x;
  const int n0 = blockIdx.x * 32;
  const int pg = tid >> 5, cg = tid & 31;
#pragma unroll
  for (int i = 0; i < 4; ++i) {
    int idx = tid + i * 256;
    int p = idx >> 5, c4 = (idx & 31) << 2;
    *(float4*)&a_lds[p][c4] = *(const float4*)&sbuf[(size_t)(n0 + p) * CC + c4];
    *(float4*)&q_lds[p][c4] = *(const float4*)&qio[(size_t)(n0 + p) * CC + c4];
  }
  __syncthreads();

  // out projection
  float acc2[4][4] = {};
#pragma unroll
  for (int kc = 0; kc < 128; kc += 32) {
    stage_wt(wt, out_w, 128, 0, kc, tid);
    __syncthreads();
    tile_fma(a_lds, pg * 4, kc, wt, cg * 4, acc2);
    __syncthreads();
  }
  {
    float4 ob = *(const float4*)&out_b[cg * 4];
#pragma unroll
    for (int i = 0; i < 4; ++i)
#pragma unroll
      for (int j = 0; j < 4; ++j)
        q_lds[pg * 4 + i][cg * 4 + j] += acc2[i][j] + f4get(ob, j);
  }
  __syncthreads();

  // LN1 in place on q_lds
  {
    int p = tid >> 3, l = tid & 7, c0 = l * 16;
    float v[16];
#pragma unroll
    for (int q4 = 0; q4 < 4; ++q4) {
      float4 t = *(const float4*)&q_lds[p][c0 + q4 * 4];
      v[q4 * 4 + 0] = t.x; v[q4 * 4 + 1] = t.y; v[q4 * 4 + 2] = t.z; v[q4 * 4 + 3] = t.w;
    }
    float s = 0.f, ss = 0.f;
#pragma unroll
    for (int i = 0; i < 16; ++i) { s += v[i]; ss += v[i] * v[i]; }
#pragma unroll
    for (int mm = 1; mm <= 4; mm <<= 1) { s += __shfl_xor(s, mm); ss += __shfl_xor(ss, mm); }
    float mu = s * (1.0f / 128.0f);
    float var = ss * (1.0f / 128.0f) - mu * mu;
    float rstd = rsqrtf(var + 1e-5f);
#pragma unroll
    for (int q4 = 0; q4 < 4; ++q4) {
      int c = c0 + q4 * 4;
      float4 g = *(const float4*)&ln1_g[c];
      float4 b = *(const float4*)&ln1_b[c];
      float4 o;
      o.x = (v[q4 * 4 + 0] - mu) * rstd * g.x + b.x;
      o.y = (v[q4 * 4 + 1] - mu) * rstd * g.y + b.y;
      o.z = (v[q4 * 4 + 2] - mu) * rstd * g.z + b.z;
      o.w = (v[q4 * 4 + 3] - mu) * rstd * g.w + b.w;
      *(float4*)&q_lds[p][c] = o;
    }
  }
  __syncthreads();

  // FFN: hidden chunks of 128, a_lds reused as h_lds
  float acc[4][4] = {};
#pragma unroll
  for (int jc = 0; jc < 4; ++jc) {
    float acch[4][4] = {};
#pragma unroll
    for (int kc = 0; kc < 128; kc += 32) {
      stage_wt(wt, w1, 128, jc * 128, kc, tid);
      __syncthreads();
      tile_fma(q_lds, pg * 4, kc, wt, cg * 4, acch);
      __syncthreads();
    }
    float4 bb = *(const float4*)&b1[jc * 128 + cg * 4];
#pragma unroll
    for (int i = 0; i < 4; ++i)
#pragma unroll
      for (int j = 0; j < 4; ++j)
        a_lds[pg * 4 + i][cg * 4 + j] = fmaxf(acch[i][j] + f4get(bb, j), 0.f);
    __syncthreads();
#pragma unroll
    for (int kc = 0; kc < 128; kc += 32) {
      stage_wt(wt, w2, 512, 0, jc * 128 + kc, tid);
      __syncthreads();
      tile_fma(a_lds, pg * 4, kc, wt, cg * 4, acc);
      __syncthreads();
    }
  }
  {
    float4 b2v = *(const float4*)&b2[cg * 4];
#pragma unroll
    for (int i = 0; i < 4; ++i)
#pragma unroll
      for (int j = 0; j < 4; ++j)
        a_lds[pg * 4 + i][cg * 4 + j] =
            q_lds[pg * 4 + i][cg * 4 + j] + acc[i][j] + f4get(b2v, j);
  }
  __syncthreads();
  // LN2 -> qio
  {
    int p = tid >> 3, l = tid & 7, c0 = l * 16;
    float v[16];
#pragma unroll
    for (int q4 = 0; q4 < 4; ++q4) {
      float4 t = *(const float4*)&a_lds[p][c0 + q4 * 4];
      v[q4 * 4 + 0] = t.x; v[q4 * 4 + 1] = t.y; v[q4 * 4 + 2] = t.z; v[q4 * 4 + 3] = t.w;
    }
    float s = 0.f, ss = 0.f;
#pragma unroll
    for (int i = 0; i < 16; ++i) { s += v[i]; ss += v[i] * v[i]; }
#pragma unroll
    for (int mm = 1; mm <= 4; mm <<= 1) { s += __shfl_xor(s, mm); ss += __shfl_xor(ss, mm); }
    float mu = s * (1.0f / 128.0f);
    float var = ss * (1.0f / 128.0f) - mu * mu;
    float rstd = rsqrtf(var + 1e-5f);
#pragma unroll
    for (int q4 = 0; q4 < 4; ++q4) {
      int c = c0 + q4 * 4;
      float4 g = *(const float4*)&g2[c];
      float4 b = *(const float4*)&bb2[c];
      float4 o;
      o.x = (v[q4 * 4 + 0] - mu) * rstd * g.x + b.x;
      o.y = (v[q4 * 4 + 1] - mu) * rstd * g.y + b.y;
      o.z = (v[q4 * 4 + 2] - mu) * rstd * g.z + b.z;
      o.w = (v[q4 * 4 + 3] - mu) * rstd * g.w + b.w;
      *(float4*)&qio[(size_t)(n0 + p) * CC + c] = o;
    }
  }
}

// ---------------------------------------------------------------- final fuse

__global__ __launch_bounds__(256, 3) void k_final(
    const float* __restrict__ pf, const float* __restrict__ q,
    const float* __restrict__ pt_w, const float* __restrict__ pt_b,
    const float* __restrict__ pt_s, const float* __restrict__ pt_t,
    const float* __restrict__ fuse_w, const float* __restrict__ fuse_b,
    const float* __restrict__ fuse_s, const float* __restrict__ fuse_t,
    float* __restrict__ outp) {
  __shared__ float a_lds[32][132];   // pf tile, then relu(pts_pre)
  __shared__ float q_lds[32][132];   // relu(q)
  __shared__ float wt[32][132];
  const int tid = threadIdx.x;
  const int n0 = blockIdx.x * 32;
  const int pg = tid >> 5, cg = tid & 31;
#pragma unroll
  for (int i = 0; i < 4; ++i) {
    int idx = tid + i * 256;
    int p = idx >> 5, c4 = (idx & 31) << 2;
    *(float4*)&a_lds[p][c4] = *(const float4*)&pf[(size_t)(n0 + p) * CC + c4];
    float4 qq = *(const float4*)&q[(size_t)(n0 + p) * CC + c4];
    qq.x = fmaxf(qq.x, 0.f); qq.y = fmaxf(qq.y, 0.f);
    qq.z = fmaxf(qq.z, 0.f); qq.w = fmaxf(qq.w, 0.f);
    *(float4*)&q_lds[p][c4] = qq;
  }
  __syncthreads();
  float accP[4][4] = {};
#pragma unroll
  for (int kc = 0; kc < 128; kc += 32) {
    stage_wt(wt, pt_w, 128, 0, kc, tid);
    __syncthreads();
    tile_fma(a_lds, pg * 4, kc, wt, cg * 4, accP);
    __syncthreads();
  }
  {
    float4 pb = *(const float4*)&pt_b[cg * 4];
    float4 ps = *(const float4*)&pt_s[cg * 4];
    float4 pt4 = *(const float4*)&pt_t[cg * 4];
#pragma unroll
    for (int i = 0; i < 4; ++i)
#pragma unroll
      for (int j = 0; j < 4; ++j)
        a_lds[pg * 4 + i][cg * 4 + j] =
            fmaxf((accP[i][j] + f4get(pb, j)) * f4get(ps, j) + f4get(pt4, j), 0.f);
  }
  __syncthreads();
  float acc[4][4] = {};
#pragma unroll
  for (int kc = 0; kc < 128; kc += 32) {
    stage_wt(wt, fuse_w, 256, 0, kc, tid);
    __syncthreads();
    tile_fma(a_lds, pg * 4, kc, wt, cg * 4, acc);
    __syncthreads();
  }
#pragma unroll
  for (int kc = 0; kc < 128; kc += 32) {
    stage_wt(wt, fuse_w, 256, 0, 128 + kc, tid);
    __syncthreads();
    tile_fma(q_lds, pg * 4, kc, wt, cg * 4, acc);
    __syncthreads();
  }
  {
    float4 fb = *(const float4*)&fuse_b[cg * 4];
    float4 fs = *(const float4*)&fuse_s[cg * 4];
    float4 ft = *(const float4*)&fuse_t[cg * 4];
#pragma unroll
    for (int i = 0; i < 4; ++i) {
      float4 o;
      o.x = fmaxf((acc[i][0] + fb.x) * fs.x + ft.x, 0.f);
      o.y = fmaxf((acc[i][1] + fb.y) * fs.y + ft.y, 0.f);
      o.z = fmaxf((acc[i][2] + fb.z) * fs.z + ft.z, 0.f);
      o.w = fmaxf((acc[i][3] + fb.w) * fs.w + ft.w, 0.f);
      *(float4*)&outp[(size_t)(n0 + pg * 4 + i) * CC + cg * 4] = o;
    }
  }
}

// ---------------------------------------------------------------- launch

extern "C" void kernel_launch(void* const* d_in, const int* in_sizes, int n_in,
                              void* d_out, int out_size, void* d_ws, size_t ws_size,
                              hipStream_t stream) {
  const float* pf    = (const float*)d_in[0];
  const float* img   = (const float*)d_in[1];
  const int*   grid  = (const int*)d_in[2];
  const float* pkp_w = (const float*)d_in[3];
  const float* pkp_b = (const float*)d_in[4];
  const float* pkp_s = (const float*)d_in[5];
  const float* pkp_t = (const float*)d_in[6];
  const float* fc_w  = (const float*)d_in[7];
  const float* fc_b  = (const float*)d_in[8];
  const float* fc_s  = (const float*)d_in[9];
  const float* fc_t  = (const float*)d_in[10];
  const float* pt_w  = (const float*)d_in[11];
  const float* pt_b  = (const float*)d_in[12];
  const float* pt_s  = (const float*)d_in[13];
  const float* pt_t  = (const float*)d_in[14];
  const float* val_w = (const float*)d_in[15];
  const float* val_b = (const float*)d_in[16];
  const float* off_w = (const float*)d_in[17];
  const float* off_b = (const float*)d_in[18];
  const float* aw_w  = (const float*)d_in[19];
  const float* aw_b  = (const float*)d_in[20];
  const float* out_w = (const float*)d_in[21];
  const float* out_b = (const float*)d_in[22];
  const float* ln1_g = (const float*)d_in[23];
  const float* ln1_b = (const float*)d_in[24];
  const float* ffn_w1 = (const float*)d_in[25];
  const float* ffn_b1 = (const float*)d_in[26];
  const float* ffn_w2 = (const float*)d_in[27];
  const float* ffn_b2 = (const float*)d_in[28];
  const float* ln2_g = (const float*)d_in[29];
  const float* ln2_b = (const float*)d_in[30];
  const float* fuse_w = (const float*)d_in[31];
  const float* fuse_b = (const float*)d_in[32];
  const float* fuse_s = (const float*)d_in[33];
  const float* fuse_t = (const float*)d_in[34];
  float* outp = (float*)d_out;

  char* ws = (char*)d_ws;
  int* stats    = (int*)ws;
  __half* vmapT = (__half*)(ws + 256);                      // 4*H*W*32 halves = 31.5 MB
  float* imgT   = (float*)(ws + 256 + (size_t)4 * HWPX * 32 * sizeof(__half));
  float* sbuf   = imgT;                                     // alias: imgT dead after k_query
  float* qbuf   = imgT + (size_t)HWPX * CC;
  float* pxyb   = qbuf + (size_t)NPTS * CC;
  float* awb    = pxyb + (size_t)NPTS * 32;

  k_stats_init<<<1, 64, 0, stream>>>(stats);
  k_stats<<<256, 256, 0, stream>>>(grid, stats);
  k_vmap<<<HWPX / 64, 256, 0, stream>>>(img, val_w, val_b, vmapT, imgT);
  k_query<<<NPTS / 32, 256, 0, stream>>>(pf, grid, imgT, stats,
                                         pkp_w, pkp_b, pkp_s, pkp_t,
                                         fc_w, fc_b, fc_s, fc_t,
                                         off_w, off_b, aw_w, aw_b,
                                         qbuf, pxyb, awb);
  k_sample<<<(NPTS * 8) / 256, 256, 0, stream>>>(pxyb, awb, vmapT, sbuf);
  k_ffn2<<<NPTS / 32, 256, 0, stream>>>(sbuf, qbuf, out_w, out_b, ln1_g, ln1_b,
                                        ffn_w1, ffn_b1, ffn_w2, ffn_b2, ln2_g, ln2_b);
  k_final<<<NPTS / 32, 256, 0, stream>>>(pf, qbuf, pt_w, pt_b, pt_s, pt_t,
                                         fuse_w, fuse_b, fuse_s, fuse_t, outp);
}